// Round 9
// baseline (298.771 us; speedup 1.0000x reference)
//
#include <hip/hip_runtime.h>

constexpr int DEG = 31;        // neighbors per node
constexpr int NEV = 32;        // events per node (self + neighbors)
constexpr int TH  = 16;        // threshold: dp[0..15] + absorbing "over"
constexpr int BLK = 256;       // fallback block size
constexpr int TBL = 1 << 20;   // u8 table entries (padded >= n)

// scan kernel geometry
constexpr int CH    = 1 << 17;     // 128 KB LDS chunk
constexpr int NPASS = TBL / CH;    // 8 passes
constexpr int BLK4  = 1024;        // 16 waves
constexpr int NPB4  = 2048;        // 2 nodes per thread

typedef int  vint4  __attribute__((ext_vector_type(4)));

__global__ void zero_out_kernel(float* out) {
    if (threadIdx.x == 0) out[0] = 0.0f;
}

__device__ __forceinline__ float fast_sigmoid(float x) {
    return 1.0f / (1.0f + __expf(-x));
}

// ---- phase 1: u8 table tbl[i] = rint(sigmoid(gains[i])*255) + zero out ----
__global__ __launch_bounds__(256)
void build_table_kernel(const float* __restrict__ gains,
                        unsigned* __restrict__ tbl4,
                        float* __restrict__ out, int n) {
    const int t = blockIdx.x * 256 + threadIdx.x;
    if (t == 0) out[0] = 0.0f;
    if (t < TBL / 4) {
        unsigned w = 0;
        #pragma unroll
        for (int k = 0; k < 4; ++k) {
            const int i = 4 * t + k;
            const float p = (i < n) ? fast_sigmoid(gains[i]) : 0.0f;
            const unsigned b = __float2uint_rn(p * 255.0f);
            w |= (b & 0xFFu) << (8 * k);
        }
        tbl4[t] = w;
    }
}

// Poisson-binomial DP from packed u8 probability bytes (original j-order ->
// bit-identical per-node result vs all previous passing kernels).
__device__ __forceinline__ float node_dp(float g, const unsigned w[8]) {
    const float p0 = fast_sigmoid(g);
    float dp[TH];
    dp[0] = 1.0f;
    #pragma unroll
    for (int k = 1; k < TH; ++k) dp[k] = 0.0f;
    float over = 0.0f;
    #pragma unroll
    for (int j = 0; j < NEV; ++j) {
        float pj;
        if (j == 0) {
            pj = p0;
        } else {
            const unsigned b = (w[(j - 1) >> 2] >> (((j - 1) & 3) * 8)) & 0xFFu;
            pj = (float)b * (1.0f / 255.0f);
        }
        if (j >= TH - 1) over = fmaf(dp[TH - 1], pj, over);
        const int kmax = (j + 1 < TH - 1) ? (j + 1) : (TH - 1);
        #pragma unroll
        for (int k = kmax; k >= 1; --k)
            dp[k] = fmaf(pj, dp[k - 1] - dp[k], dp[k]);
        dp[0] = fmaf(-pj, dp[0], dp[0]);
    }
    return fmaf(0.25f, p0, -over);
}

// ---- phase 2: streaming-scan gather, v2 ----
// r8 (126 us) improvements, both funded by global_load_lds staging:
//  - staging is HBM/L2 -> LDS direct: no pf registers, no ds_write insts
//    (r8 paid the LDS write pipe twice: reg->LDS after global->reg)
//  - freed VGPRs fund 2 nodes/thread: the fixed 1 MB sweep + 16 barriers
//    per block amortize over 2048 nodes instead of 1024
// Plain __syncthreads() everywhere: its vmcnt(0) drain is exactly the wait
// the freshly-staged chunk needs (no held-in-flight loads in this design).
__global__ __launch_bounds__(BLK4, 4)
void pgl4_kernel(const float* __restrict__ gains,
                 const int*   __restrict__ nbr,
                 const unsigned char* __restrict__ tbl,
                 float*       __restrict__ out, int n) {
    __shared__ __align__(16) unsigned char smem[CH];   // 128 KB multi-purpose

    const int tid        = threadIdx.x;
    const int wid        = tid >> 6;                   // wave id 0..15
    const int lane       = tid & 63;
    const int blockStart = blockIdx.x * NPB4;

    // ---- bounce neighbor rows through LDS into registers, 2 rounds ----
    unsigned idxA[DEG], idxB[DEG];
    #pragma unroll
    for (int j = 0; j < DEG; ++j) { idxA[j] = 0u; idxB[j] = 0u; }

    #pragma unroll 1
    for (int r = 0; r < 2; ++r) {
        const int rowBase = blockStart + r * 1024;
        const int rows    = min(1024, max(0, n - rowBase));
        const int elems   = rows * DEG;
        __syncthreads();
        {
            const size_t base = (size_t)rowBase * DEG;
            const vint4* nb4  = (const vint4*)(nbr + base);  // 1024*31*4 % 16 == 0
            vint4* s4 = (vint4*)smem;
            const int nvec = elems >> 2;
            for (int v = tid; v < nvec; v += BLK4)
                s4[v] = __builtin_nontemporal_load(nb4 + v);
            for (int e = (nvec << 2) + tid; e < elems; e += BLK4)
                ((int*)smem)[e] = __builtin_nontemporal_load(nbr + base + e);
        }
        __syncthreads();
        if (tid < rows) {
            const int* row = (const int*)smem + tid * DEG;  // stride-31: conflict-free
            if (r == 0) {
                #pragma unroll
                for (int j = 0; j < DEG; ++j) idxA[j] = (unsigned)row[j];
            } else {
                #pragma unroll
                for (int j = 0; j < DEG; ++j) idxB[j] = (unsigned)row[j];
            }
        }
    }

    unsigned wA[8], wB[8];
    #pragma unroll
    for (int q = 0; q < 8; ++q) { wA[q] = 0u; wB[q] = 0u; }

    // ---- pass loop ----
    #pragma unroll 1
    for (int c = 0; c < NPASS; ++c) {
        __syncthreads();   // prev probes / bounce reads done before overwrite

        // async stage chunk c: 8 x global_load_lds(16B) per thread.
        // LDS dst is wave-uniform (wid,q only) + implicit lane*16: legal form.
        {
            const size_t gbase = (size_t)c * (size_t)CH;
            #pragma unroll
            for (int q = 0; q < 8; ++q) {
                const int off = q * 16384 + wid * 1024;
                const unsigned char* src = tbl + gbase + (size_t)off + (size_t)lane * 16;
                __builtin_amdgcn_global_load_lds(
                    (const __attribute__((address_space(1))) void*)src,
                    (__attribute__((address_space(3))) void*)(smem + off),
                    16, 0, 0);
            }
        }
        __syncthreads();   // vmcnt(0) drain + rendezvous: chunk c visible

        // ---- branchless batched probes: 8 A + 8 B reads in flight per batch
        const unsigned cbase = (unsigned)c * (unsigned)CH;
        #pragma unroll
        for (int jb = 0; jb < DEG; jb += 8) {
            const int m = (jb + 8 <= DEG) ? 8 : (DEG - jb);
            unsigned rA[8], bA[8], rB[8], bB[8];
            #pragma unroll
            for (int u = 0; u < m; ++u) {
                rA[u] = idxA[jb + u] - cbase;            // unsigned wrap = chunk test
                const unsigned aA = (rA[u] < (unsigned)CH) ? rA[u] : (unsigned)(CH - 1);
                bA[u] = (unsigned)smem[aA];
                rB[u] = idxB[jb + u] - cbase;
                const unsigned aB = (rB[u] < (unsigned)CH) ? rB[u] : (unsigned)(CH - 1);
                bB[u] = (unsigned)smem[aB];
            }
            #pragma unroll
            for (int u = 0; u < m; ++u) {
                const int j = jb + u;
                wA[j >> 2] |= (rA[u] < (unsigned)CH)
                                  ? ((bA[u] & 0xFFu) << ((j & 3) * 8)) : 0u;
                wB[j >> 2] |= (rB[u] < (unsigned)CH)
                                  ? ((bB[u] & 0xFFu) << ((j & 3) * 8)) : 0u;
            }
        }
    }

    // ---- DP + reduction ----
    float local = 0.0f;
    const int iA = blockStart + tid;
    const int iB = blockStart + 1024 + tid;
    if (iA < n) local += node_dp(__builtin_nontemporal_load(gains + iA), wA);
    if (iB < n) local += node_dp(__builtin_nontemporal_load(gains + iB), wB);

    #pragma unroll
    for (int o = 32; o > 0; o >>= 1) local += __shfl_down(local, o, 64);
    __syncthreads();                         // last probes done before smem reuse
    if ((tid & 63) == 0) ((float*)smem)[tid >> 6] = local;
    __syncthreads();
    if (tid == 0) {
        float s = 0.0f;
        #pragma unroll
        for (int wv = 0; wv < BLK4 / 64; ++wv) s += ((float*)smem)[wv];
        atomicAdd(out, s);
    }
}

// ---- fallback (ws too small): f32 direct gather ----
__global__ __launch_bounds__(BLK)
void pgl_direct_kernel(const float* __restrict__ gains,
                       const int*   __restrict__ nbr,
                       float*       __restrict__ out, int n) {
    __shared__ int s_idx[BLK * DEG];
    __shared__ float s_red[BLK / 64];
    const int tid = threadIdx.x;
    const int blockStart = blockIdx.x * BLK;
    const int rows  = min(BLK, n - blockStart);
    const int elems = rows * DEG;
    const int base  = blockStart * DEG;
    const int4* nb4 = (const int4*)(nbr + base);
    int4* s4 = (int4*)s_idx;
    const int nvec = elems >> 2;
    for (int v = tid; v < nvec; v += BLK) s4[v] = nb4[v];
    for (int e = (nvec << 2) + tid; e < elems; e += BLK) s_idx[e] = nbr[base + e];
    __syncthreads();
    float local = 0.0f;
    const int i = blockStart + tid;
    if (i < n) {
        const int* row = s_idx + tid * DEG;
        float dp[TH];
        dp[0] = 1.0f;
        #pragma unroll
        for (int k = 1; k < TH; ++k) dp[k] = 0.0f;
        float over = 0.0f;
        const float p0 = fast_sigmoid(gains[i]);
        #pragma unroll
        for (int j = 0; j < NEV; ++j) {
            const float pj = (j == 0) ? p0 : fast_sigmoid(gains[row[j - 1]]);
            if (j >= TH - 1) over = fmaf(dp[TH - 1], pj, over);
            const int kmax = (j + 1 < TH - 1) ? (j + 1) : (TH - 1);
            #pragma unroll
            for (int k = kmax; k >= 1; --k)
                dp[k] = fmaf(pj, dp[k - 1] - dp[k], dp[k]);
            dp[0] = fmaf(-pj, dp[0], dp[0]);
        }
        local = fmaf(0.25f, p0, -over);
    }
    #pragma unroll
    for (int o = 32; o > 0; o >>= 1) local += __shfl_down(local, o, 64);
    if ((tid & 63) == 0) s_red[tid >> 6] = local;
    __syncthreads();
    if (tid == 0) {
        float s = 0.0f;
        #pragma unroll
        for (int w = 0; w < BLK / 64; ++w) s += s_red[w];
        atomicAdd(out, s);
    }
}

extern "C" void kernel_launch(void* const* d_in, const int* in_sizes, int n_in,
                              void* d_out, int out_size, void* d_ws, size_t ws_size,
                              hipStream_t stream) {
    const float* gains = (const float*)d_in[0];
    const int*   nbr   = (const int*)d_in[1];
    float*       out   = (float*)d_out;
    const int n = in_sizes[0];

    if (ws_size >= (size_t)TBL && n <= TBL) {
        unsigned char* tbl = (unsigned char*)d_ws;
        build_table_kernel<<<(TBL / 4 + 255) / 256, 256, 0, stream>>>(
            gains, (unsigned*)tbl, out, n);
        const int grid4 = (n + NPB4 - 1) / NPB4;
        pgl4_kernel<<<grid4, BLK4, 0, stream>>>(gains, nbr, tbl, out, n);
    } else {
        zero_out_kernel<<<1, 64, 0, stream>>>(out);
        const int grid = (n + BLK - 1) / BLK;
        pgl_direct_kernel<<<grid, BLK, 0, stream>>>(gains, nbr, out, n);
    }
}